// Round 5
// baseline (368.249 us; speedup 1.0000x reference)
//
#include <hip/hip_runtime.h>
#include <hip/hip_bf16.h>
#include <math.h>

// ChannelMambaBlock fused — Round 5: barrier-free wave-private pixels
// B=4, C=192, H=128, W=128, K=4, DSTATE=8, DTRANK=12
// Block = 4 waves; EACH WAVE privately owns 16 consecutive-W pixels end-to-end.
// grid = 1024 blocks = exactly 4 blocks/CU (whole grid resident, no tail).
// ZERO __syncthreads: LN reduces via __shfl_xor; per-wave LDS regions are
// private (ds ordering via lgkmcnt only). z / x2 / y stay in packed-bf16 regs
// (producer/consumer MFMA tile layouts match lane-for-lane).

#define CC    192
#define HH    128
#define WW    128
#define NK    4
#define DST   8
#define DTR   12
#define NTH   256
#define SP    200         // sX row stride (400B: 16B-aligned rows)
#define SD    112         // sXD row stride (224B: 16B-aligned rows)

typedef __attribute__((ext_vector_type(8))) short bh8;   // 8 bf16 = 4 VGPR
typedef __attribute__((ext_vector_type(4))) float f4;

// bf16 weight segments inside d_ws (ushort elems)
#define OFF_WIN    0
#define OFF_SSMIN  73728        // 384*192
#define OFF_XPROJ  147456
#define OFF_SSMOUT 168960       // + 112*192
#define OFF_WOUT   205824
#define OFF_DTW    242688       // + 192*192  -> B_dt [k][c][32]
#define WTOT2      267264       // + 4*192*32
// f32 Dsum[192] at ushort offset WTOT2

#define MFMA(va, vb, vc) __builtin_amdgcn_mfma_f32_16x16x32_bf16(va, vb, vc, 0, 0, 0)

__device__ __forceinline__ float bf2f(unsigned short u) {
    union { unsigned int i; float f; } v; v.i = ((unsigned int)u) << 16; return v.f;
}
__device__ __forceinline__ unsigned short f2bf(float f) {
    __hip_bfloat16 h = __float2bfloat16(f);
    unsigned short u; __builtin_memcpy(&u, &h, 2); return u;
}
__device__ __forceinline__ unsigned int pk2(float a, float b) {
    return (unsigned int)f2bf(a) | ((unsigned int)f2bf(b) << 16);
}
__device__ __forceinline__ float lo16(unsigned int u) { return bf2f((unsigned short)(u & 0xffffu)); }
__device__ __forceinline__ float hi16(unsigned int u) { return bf2f((unsigned short)(u >> 16)); }

#define LOG2E 1.44269504f
#define LN2   0.69314718f
__device__ __forceinline__ float silu_fast(float x) {
    float e = __builtin_amdgcn_exp2f(-LOG2E * x);
    return x * __builtin_amdgcn_rcpf(1.f + e);
}
__device__ __forceinline__ float softplus_fast(float x) {
    float e = __builtin_amdgcn_exp2f(-LOG2E * fabsf(x));
    return fmaxf(x, 0.f) + LN2 * __builtin_amdgcn_logf(1.f + e);
}

extern "C" __global__ void prep_w(const float* __restrict__ w_in,
                                  const float* __restrict__ ssm_in_w,
                                  const float* __restrict__ x_proj_w,
                                  const float* __restrict__ ssm_out_w,
                                  const float* __restrict__ w_out,
                                  const float* __restrict__ dt_w,
                                  const float* __restrict__ dt_b,
                                  const float* __restrict__ Ds,
                                  unsigned short* __restrict__ wb)
{
    int i = blockIdx.x * NTH + threadIdx.x;
    if (i < OFF_DTW) {
        float v;
        if      (i < OFF_XPROJ ) v = (i < OFF_SSMIN) ? w_in[i] : ssm_in_w[i - OFF_SSMIN];
        else if (i < OFF_SSMOUT) v = x_proj_w[i - OFF_XPROJ];
        else if (i < OFF_WOUT  ) v = ssm_out_w[i - OFF_SSMOUT];
        else                     v = w_out[i - OFF_WOUT];
        wb[i] = f2bf(v);
    } else if (i < WTOT2) {
        int j  = i - OFF_DTW;
        int r  = j & 31;
        int kc = j >> 5;
        float v = (r < DTR) ? dt_w[kc * DTR + r]
                            : (r == 31 ? dt_b[kc] : 0.f);
        wb[i] = f2bf(v);
    } else if (i < WTOT2 + CC) {
        int c = i - WTOT2;
        float* dsum = (float*)(wb + WTOT2);
        dsum[c] = Ds[c] + Ds[CC + c] + Ds[2*CC + c] + Ds[3*CC + c];
    }
}

template<int NT>
__device__ __forceinline__ void gemmN(const bh8 a[6], const unsigned short* wp,
                                      f4 acc[NT]) {
#pragma unroll
    for (int ks = 0; ks < 6; ++ks)
#pragma unroll
        for (int j = 0; j < NT; ++j) {
            bh8 bf = *(const bh8*)(wp + (size_t)j * 16 * CC + ks * 32);
            acc[j] = MFMA(a[ks], bf, acc[j]);
        }
}

extern "C" __global__ void __launch_bounds__(NTH, 4)
mamba_fused(const float* __restrict__ x,
            const float* __restrict__ norm_w,  const float* __restrict__ norm_b,
            const float* __restrict__ out_norm_w, const float* __restrict__ out_norm_b,
            const unsigned short* __restrict__ wsb,
            float* __restrict__ out)
{
    __shared__ __align__(16) unsigned short sX [4][16][SP];   // 25600 B
    __shared__ __align__(16) unsigned short sXD[4][16][SD];   // 14336 B
    __shared__ __align__(16) float sbc[4][NK][16];            //  1024 B => 40960 B

    const int tid  = threadIdx.x;
    const int lane = tid & 63;
    const int wv   = tid >> 6;
    const int frow = lane & 15;
    const int kb   = lane >> 4;
    const int pxb  = kb * 4;

    const int t   = blockIdx.x;          // 1024 blocks
    const int b   = t >> 8;
    const int rem = t & 255;
    const int h   = rem >> 1;
    const int w0  = (rem & 1) * 64 + wv * 16;   // wave's first pixel (w coord)

    unsigned short (*mX)[SP]  = sX[wv];
    unsigned short (*mXD)[SD] = sXD[wv];
    float (*mbc)[16]          = sbc[wv];

    const float* dsum = (const float*)(wsb + WTOT2);

    // persistent packed-bf16 registers (D-layout: tile j <-> chan j*16+frow,
    // rows pxb..pxb+3): x2p = silu(x2), zp = silu(z)
    unsigned int x2p[12][2], zp[12][2];

    // ---------------- LN1: load x, normalize -> mX = xn (bf16) ------------------
    {
        const int c0 = kb * 48;
        const size_t base = (((size_t)b * CC + c0) * HH + h) * WW + w0 + frow;
        float v[48];
        float sum = 0.f, sq = 0.f;
#pragma unroll
        for (int i = 0; i < 48; ++i) {
            v[i] = x[base + (size_t)i * (HH * WW)];
            sum += v[i]; sq += v[i] * v[i];
        }
        sum += __shfl_xor(sum, 16); sum += __shfl_xor(sum, 32);
        sq  += __shfl_xor(sq , 16); sq  += __shfl_xor(sq , 32);
        float mu = sum * (1.f / CC);
        float rs = rsqrtf(sq * (1.f / CC) - mu * mu + 1e-5f);
#pragma unroll
        for (int i = 0; i < 48; ++i) {
            int c = c0 + i;
            mX[frow][c] = f2bf((v[i] - mu) * rs * norm_w[c] + norm_b[c]);
        }
    }

    bh8 a[6];
    auto load_a = [&]() {
#pragma unroll
        for (int ks = 0; ks < 6; ++ks)
            a[ks] = *(const bh8*)(&mX[frow][ks * 32 + kb * 8]);
    };

    // ---------------- GEMM1: p = xn @ w_in^T -> mX = x1, x2p = silu(x2) ---------
    {
        load_a();
        const unsigned short* wB = wsb + OFF_WIN;
#pragma unroll
        for (int g = 0; g < 6; ++g) {
            f4 acc[4] = {{0,0,0,0},{0,0,0,0},{0,0,0,0},{0,0,0,0}};
            gemmN<4>(a, wB + (size_t)(g * 64 + frow) * CC + kb * 8, acc);
#pragma unroll
            for (int j = 0; j < 4; ++j) {
                int tile = g * 4 + j;
                int o = tile * 16 + frow;
                if (tile < 12) {
#pragma unroll
                    for (int r = 0; r < 4; ++r) mX[pxb + r][o] = f2bf(acc[j][r]);
                } else {
                    x2p[tile - 12][0] = pk2(silu_fast(acc[j][0]), silu_fast(acc[j][1]));
                    x2p[tile - 12][1] = pk2(silu_fast(acc[j][2]), silu_fast(acc[j][3]));
                }
            }
        }
    }

    // ---------------- GEMM2: u = x1 @ ssm_in^T -> mX = silu(xss), zp = silu(z) --
    {
        load_a();                       // x1
        const unsigned short* wB = wsb + OFF_SSMIN;
#pragma unroll
        for (int g = 0; g < 6; ++g) {
            f4 acc[4] = {{0,0,0,0},{0,0,0,0},{0,0,0,0},{0,0,0,0}};
            gemmN<4>(a, wB + (size_t)(g * 64 + frow) * CC + kb * 8, acc);
#pragma unroll
            for (int j = 0; j < 4; ++j) {
                int tile = g * 4 + j;
                int o = tile * 16 + frow;
                if (tile < 12) {
#pragma unroll
                    for (int r = 0; r < 4; ++r)
                        mX[pxb + r][o] = f2bf(silu_fast(acc[j][r]));
                } else {
                    zp[tile - 12][0] = pk2(silu_fast(acc[j][0]), silu_fast(acc[j][1]));
                    zp[tile - 12][1] = pk2(silu_fast(acc[j][2]), silu_fast(acc[j][3]));
                }
            }
        }
    }

    // ---------------- GEMM3: xd = xss @ x_proj^T (112) -> mXD -------------------
    {
        load_a();                       // silu(xss)
        const unsigned short* wB = wsb + OFF_XPROJ;
        {
            f4 acc[4] = {{0,0,0,0},{0,0,0,0},{0,0,0,0},{0,0,0,0}};
            gemmN<4>(a, wB + (size_t)frow * CC + kb * 8, acc);
#pragma unroll
            for (int j = 0; j < 4; ++j) {
                int o = j * 16 + frow;
#pragma unroll
                for (int r = 0; r < 4; ++r) mXD[pxb + r][o] = f2bf(acc[j][r]);
            }
        }
        {
            f4 acc[3] = {{0,0,0,0},{0,0,0,0},{0,0,0,0}};
            gemmN<3>(a, wB + (size_t)(64 + frow) * CC + kb * 8, acc);
#pragma unroll
            for (int j = 0; j < 3; ++j) {
                int o = (4 + j) * 16 + frow;
#pragma unroll
                for (int r = 0; r < 4; ++r) mXD[pxb + r][o] = f2bf(acc[j][r]);
            }
        }
    }

    // ---------------- bc[k][px] = dot(Bv, Cv) -----------------------------------
    {
        const unsigned short* rp = &mXD[frow][kb * 28 + DTR];
        float acc = 0.f;
#pragma unroll
        for (int s = 0; s < DST; ++s)
            acc += bf2f(rp[s]) * bf2f(rp[DST + s]);
        mbc[kb][frow] = acc;
    }

    // ---------------- dt-MFMA: y = xss * (sum_k bc*softplus(.) + Dsum) ----------
    unsigned int yp[12][2];
    {
        bh8 adt[NK];
#pragma unroll
        for (int k = 0; k < NK; ++k) {
            const unsigned short* rp = &mXD[frow][k * 28];
            bh8 vv;
            if (kb == 0) {
                ushort4 lo = *(const ushort4*)(rp);
                ushort4 hi = *(const ushort4*)(rp + 4);
                vv = bh8{(short)lo.x,(short)lo.y,(short)lo.z,(short)lo.w,
                         (short)hi.x,(short)hi.y,(short)hi.z,(short)hi.w};
            } else if (kb == 1) {
                ushort4 lo = *(const ushort4*)(rp + 8);
                vv = bh8{(short)lo.x,(short)lo.y,(short)lo.z,(short)lo.w,0,0,0,0};
            } else if (kb == 2) {
                vv = bh8{0,0,0,0,0,0,0,0};
            } else {
                vv = bh8{0,0,0,0,0,0,0,(short)0x3F80};   // bf16 1.0 -> col 31 (dt_b)
            }
            adt[k] = vv;
        }
        f4 bck[NK];
#pragma unroll
        for (int k = 0; k < NK; ++k) bck[k] = *(const f4*)(&mbc[k][pxb]);

        const unsigned short* wDT = wsb + OFF_DTW;
#pragma unroll
        for (int ct = 0; ct < 12; ++ct) {
            int c = ct * 16 + frow;
            f4 g = {0.f,0.f,0.f,0.f};
#pragma unroll
            for (int k = 0; k < NK; ++k) {
                bh8 bf = *(const bh8*)(wDT + (((size_t)(k * CC + c)) << 5) + kb * 8);
                f4 d = {0.f,0.f,0.f,0.f};
                d = MFMA(adt[k], bf, d);
#pragma unroll
                for (int r = 0; r < 4; ++r)
                    g[r] += bck[k][r] * softplus_fast(d[r]);
            }
            float ds = dsum[c];
            float y0 = bf2f(mX[pxb + 0][c]) * (g[0] + ds);
            float y1 = bf2f(mX[pxb + 1][c]) * (g[1] + ds);
            float y2 = bf2f(mX[pxb + 2][c]) * (g[2] + ds);
            float y3 = bf2f(mX[pxb + 3][c]) * (g[3] + ds);
            yp[ct][0] = pk2(y0, y1);
            yp[ct][1] = pk2(y2, y3);
        }
    }

    // ---------------- LN2 over y (per pixel), * z -> mX = yz --------------------
    {
        f4 sum = {0,0,0,0}, sq = {0,0,0,0};
#pragma unroll
        for (int ct = 0; ct < 12; ++ct) {
            float y0 = lo16(yp[ct][0]), y1 = hi16(yp[ct][0]);
            float y2 = lo16(yp[ct][1]), y3 = hi16(yp[ct][1]);
            sum[0] += y0; sq[0] += y0 * y0;
            sum[1] += y1; sq[1] += y1 * y1;
            sum[2] += y2; sq[2] += y2 * y2;
            sum[3] += y3; sq[3] += y3 * y3;
        }
#pragma unroll
        for (int m = 1; m < 16; m <<= 1) {
#pragma unroll
            for (int r = 0; r < 4; ++r) {
                sum[r] += __shfl_xor(sum[r], m);
                sq[r]  += __shfl_xor(sq[r],  m);
            }
        }
        f4 mu, rs;
#pragma unroll
        for (int r = 0; r < 4; ++r) {
            mu[r] = sum[r] * (1.f / CC);
            rs[r] = rsqrtf(sq[r] * (1.f / CC) - mu[r] * mu[r] + 1e-5f);
        }
#pragma unroll
        for (int ct = 0; ct < 12; ++ct) {
            int c = ct * 16 + frow;
            float wn = out_norm_w[c], bn = out_norm_b[c];
            float y0 = lo16(yp[ct][0]), y1 = hi16(yp[ct][0]);
            float y2 = lo16(yp[ct][1]), y3 = hi16(yp[ct][1]);
            float z0 = lo16(zp[ct][0]), z1 = hi16(zp[ct][0]);
            float z2 = lo16(zp[ct][1]), z3 = hi16(zp[ct][1]);
            mX[pxb + 0][c] = f2bf(((y0 - mu[0]) * rs[0] * wn + bn) * z0);
            mX[pxb + 1][c] = f2bf(((y1 - mu[1]) * rs[1] * wn + bn) * z1);
            mX[pxb + 2][c] = f2bf(((y2 - mu[2]) * rs[2] * wn + bn) * z2);
            mX[pxb + 3][c] = f2bf(((y3 - mu[3]) * rs[3] * wn + bn) * z3);
        }
    }

    // ---------------- GEMM4: s = yz @ ssm_out^T; mX = s * silu(x2) --------------
    {
        load_a();                       // yz
        const unsigned short* wB = wsb + OFF_SSMOUT;
#pragma unroll
        for (int g = 0; g < 3; ++g) {
            f4 acc[4] = {{0,0,0,0},{0,0,0,0},{0,0,0,0},{0,0,0,0}};
            gemmN<4>(a, wB + (size_t)(g * 64 + frow) * CC + kb * 8, acc);
#pragma unroll
            for (int j = 0; j < 4; ++j) {
                int tile = g * 4 + j;
                int o = tile * 16 + frow;
                mX[pxb + 0][o] = f2bf(acc[j][0] * lo16(x2p[tile][0]));
                mX[pxb + 1][o] = f2bf(acc[j][1] * hi16(x2p[tile][0]));
                mX[pxb + 2][o] = f2bf(acc[j][2] * lo16(x2p[tile][1]));
                mX[pxb + 3][o] = f2bf(acc[j][3] * hi16(x2p[tile][1]));
            }
        }
    }

    // ---------------- GEMM5: o = (s*x2) @ w_out^T; out = x + o ------------------
    {
        load_a();                       // s*x2
        const unsigned short* wB = wsb + OFF_WOUT;
#pragma unroll
        for (int g = 0; g < 3; ++g) {
            f4 acc[4] = {{0,0,0,0},{0,0,0,0},{0,0,0,0},{0,0,0,0}};
            gemmN<4>(a, wB + (size_t)(g * 64 + frow) * CC + kb * 8, acc);
#pragma unroll
            for (int j = 0; j < 4; ++j) {
                int o = (g * 4 + j) * 16 + frow;
                const size_t g0 = (((size_t)b * CC + o) * HH + h) * WW + w0 + pxb;
                float4 xv = *(const float4*)(x + g0);
                float4 ov;
                ov.x = xv.x + acc[j][0];
                ov.y = xv.y + acc[j][1];
                ov.z = xv.z + acc[j][2];
                ov.w = xv.w + acc[j][3];
                *(float4*)(out + g0) = ov;
            }
        }
    }
}

extern "C" void kernel_launch(void* const* d_in, const int* in_sizes, int n_in,
                              void* d_out, int out_size, void* d_ws, size_t ws_size,
                              hipStream_t stream) {
    const float* x          = (const float*)d_in[0];
    const float* norm_w     = (const float*)d_in[1];
    const float* norm_b     = (const float*)d_in[2];
    const float* w_in       = (const float*)d_in[3];
    const float* ssm_in_w   = (const float*)d_in[4];
    const float* x_proj_w   = (const float*)d_in[5];
    const float* dt_w       = (const float*)d_in[6];
    const float* dt_b       = (const float*)d_in[7];
    // d_in[8] = A_logs : unused by the reference computation
    const float* Ds         = (const float*)d_in[9];
    const float* out_norm_w = (const float*)d_in[10];
    const float* out_norm_b = (const float*)d_in[11];
    const float* ssm_out_w  = (const float*)d_in[12];
    const float* w_out      = (const float*)d_in[13];

    unsigned short* wb = (unsigned short*)d_ws;
    int prep_n = WTOT2 + CC;
    prep_w<<<dim3((prep_n + NTH - 1) / NTH), dim3(NTH), 0, stream>>>(
        w_in, ssm_in_w, x_proj_w, ssm_out_w, w_out, dt_w, dt_b, Ds, wb);

    mamba_fused<<<dim3(1024), dim3(NTH), 0, stream>>>(
        x, norm_w, norm_b, out_norm_w, out_norm_b, wb, (float*)d_out);
}